// Round 2
// baseline (693.757 us; speedup 1.0000x reference)
//
#include <hip/hip_runtime.h>

// Problem constants
#define N_NODES 20000
#define N_ATTRS 5000
#define IN_F    512
#define OUT_F   128
#define KP      5120          // N_ATTRS padded to multiple of 32 (MFMA K)
#define KSTEPS  (KP / 32)     // 160
#define LOG2E   1.4426950408889634f

typedef _Float16 f16x8 __attribute__((ext_vector_type(8)));
typedef float    f32x4 __attribute__((ext_vector_type(4)));

__device__ __forceinline__ float fast_exp2(float x) {
    return __builtin_amdgcn_exp2f(x);
}

// ---------------------------------------------------------------------------
// Kernel 1: Wa1 = W @ a[:128], Wa2 = W @ a[128:], both pre-scaled by log2(e);
// also repack W (fp32 [512x128] row-major) into f16 MFMA B-fragment order:
// idx = ((kb*8 + nb)*64 + lane)*8 + j  holds  W[kb*32 + (lane>>4)*8 + j][nb*16 + (lane&15)]
// ---------------------------------------------------------------------------
__global__ __launch_bounds__(256) void prep_kernel(
    const float* __restrict__ W, const float* __restrict__ a,
    float* __restrict__ Wa1, float* __restrict__ Wa2, _Float16* __restrict__ Wp) {
    int gt = blockIdx.x * blockDim.x + threadIdx.x;
    if (gt < IN_F) {
        int k = gt;
        float s1 = 0.f, s2 = 0.f;
        for (int f = 0; f < OUT_F; ++f) {
            float w = W[k * OUT_F + f];
            s1 += w * a[f];
            s2 += w * a[OUT_F + f];
        }
        Wa1[k] = s1 * LOG2E;   // fold log2(e): scores live in exp2 domain
        Wa2[k] = s2 * LOG2E;
    }
    for (int idx = gt; idx < IN_F * OUT_F; idx += gridDim.x * blockDim.x) {
        int j    = idx & 7;
        int lane = (idx >> 3) & 63;
        int nb   = (idx >> 9) & 7;
        int kb   = idx >> 12;
        int k = kb * 32 + (lane >> 4) * 8 + j;
        int n = nb * 16 + (lane & 15);
        Wp[idx] = (_Float16)W[k * OUT_F + n];
    }
}

// ---------------------------------------------------------------------------
// Kernel 2: wh1[i] = node_emb[i] . Wa1  (rows 0..19999)
//           wh2[j] = attr_emb[j] . Wa2  (rows 20000..24999)
// one wave per row; lane holds 8 consecutive fp32 (two 16B loads)
// ---------------------------------------------------------------------------
__global__ __launch_bounds__(256) void wh_kernel(
    const float* __restrict__ node_emb, const float* __restrict__ attr_emb,
    const float* __restrict__ Wa1, const float* __restrict__ Wa2,
    float* __restrict__ wh1, float* __restrict__ wh2) {
    int wave = threadIdx.x >> 6, lane = threadIdx.x & 63;
    int r = blockIdx.x * 4 + wave;   // grid = 6250 -> r in [0, 25000)
    const float* src;
    const float* vec;
    float* dst;
    if (r < N_NODES) {
        src = node_emb + (size_t)r * IN_F; vec = Wa1; dst = wh1 + r;
    } else {
        int r2 = r - N_NODES;
        src = attr_emb + (size_t)r2 * IN_F; vec = Wa2; dst = wh2 + r2;
    }
    float4 ra = *reinterpret_cast<const float4*>(src + lane * 8);
    float4 rb = *reinterpret_cast<const float4*>(src + lane * 8 + 4);
    const float* vp = vec + lane * 8;
    float s = ra.x * vp[0] + ra.y * vp[1] + ra.z * vp[2] + ra.w * vp[3]
            + rb.x * vp[4] + rb.y * vp[5] + rb.z * vp[6] + rb.w * vp[7];
#pragma unroll
    for (int off = 1; off < 64; off <<= 1) s += __shfl_xor(s, off, 64);
    if (lane == 0) *dst = s;
}

// ---------------------------------------------------------------------------
// Kernel 2b: maxwh2 = max_j wh2[j]; also zero the K-pad region of wh2.
// single block.
// ---------------------------------------------------------------------------
__global__ __launch_bounds__(256) void max_kernel(
    float* __restrict__ wh2, float* __restrict__ maxp) {
    __shared__ float red[4];
    int t = threadIdx.x;
    float m = -1e30f;
    for (int j = t; j < N_ATTRS; j += 256) m = fmaxf(m, wh2[j]);
    if (t < KP - N_ATTRS) wh2[N_ATTRS + t] = 0.f;   // deterministic pad
#pragma unroll
    for (int off = 1; off < 64; off <<= 1) m = fmaxf(m, __shfl_xor(m, off, 64));
    int wave = t >> 6, lane = t & 63;
    if (lane == 0) red[wave] = m;
    __syncthreads();
    if (t == 0) *maxp = fmaxf(fmaxf(red[0], red[1]), fmaxf(red[2], red[3]));
}

// ---------------------------------------------------------------------------
// Kernel 3: V = attr_h = attr_emb @ W  [5120(pad) x 128] f16, stored directly
// in MFMA B-fragment-packed order for the main kernel:
// Vp[((kk*8 + nb)*64 + lane)*8 + jj] = V[kk*32 + (lane>>4)*8 + jj][nb*16 + (lane&15)]
// ---------------------------------------------------------------------------
__global__ __launch_bounds__(256) void attr_h_kernel(
    const float* __restrict__ attr_emb, const _Float16* __restrict__ Wp,
    _Float16* __restrict__ Vp) {
    int wave = threadIdx.x >> 6, lane = threadIdx.x & 63;
    int m = lane & 15, quad = lane >> 4;
    int j0 = (blockIdx.x * 4 + wave) * 16;  // grid = 80 -> j0 in [0, 5120)
    int j = j0 + m;
    bool valid = j < N_ATTRS;
    f32x4 acc[8];
#pragma unroll
    for (int nb = 0; nb < 8; ++nb)
#pragma unroll
        for (int t = 0; t < 4; ++t) acc[nb][t] = 0.f;
    const float* arow = attr_emb + (size_t)j * IN_F;
    for (int kk = 0; kk < IN_F / 32; ++kk) {
        f16x8 afrag;
        if (valid) {
            float4 ra = *reinterpret_cast<const float4*>(arow + kk * 32 + quad * 8);
            float4 rb = *reinterpret_cast<const float4*>(arow + kk * 32 + quad * 8 + 4);
            afrag[0] = (_Float16)ra.x; afrag[1] = (_Float16)ra.y;
            afrag[2] = (_Float16)ra.z; afrag[3] = (_Float16)ra.w;
            afrag[4] = (_Float16)rb.x; afrag[5] = (_Float16)rb.y;
            afrag[6] = (_Float16)rb.z; afrag[7] = (_Float16)rb.w;
        } else {
#pragma unroll
            for (int t = 0; t < 8; ++t) afrag[t] = (_Float16)0.f;
        }
        const _Float16* wbase = Wp + (size_t)(kk * 8) * 64 * 8;
#pragma unroll
        for (int nb = 0; nb < 8; ++nb) {
            f16x8 bfrag;
            __builtin_memcpy(&bfrag, wbase + (nb * 64 + lane) * 8, 16);
            acc[nb] = __builtin_amdgcn_mfma_f32_16x16x32_f16(afrag, bfrag, acc[nb], 0, 0, 0);
        }
    }
    // C/D layout: row = quad*4 + reg, col = lane&15 (within 16x16 tile)
#pragma unroll
    for (int nb = 0; nb < 8; ++nb) {
#pragma unroll
        for (int reg = 0; reg < 4; ++reg) {
            int jr = j0 + quad * 4 + reg;
            int n = nb * 16 + m;
            float v = (jr < N_ATTRS) ? acc[nb][reg] : 0.f;  // zero the K padding
            size_t idx = ((size_t)((jr >> 5) * 8 + nb) * 64 +
                          (((jr >> 3) & 3) * 16 + m)) * 8 + (jr & 7);
            Vp[idx] = (_Float16)v;
        }
    }
}

// ---------------------------------------------------------------------------
// Kernel 4 (main): per 16-node tile, stream feat_mat once, build P fragments
// (f16, flash-style rescaled so p <= 4096) in registers, MFMA into [16x128]
// fp32, online row-sums, normalize + ELU. 4 waves split K, LDS cross-reduce.
// ---------------------------------------------------------------------------
__global__ __launch_bounds__(256, 2) void attn_kernel(
    const int* __restrict__ feat, const float* __restrict__ wh1,
    const float* __restrict__ wh2, const float* __restrict__ maxwh2,
    const _Float16* __restrict__ Vp, float* __restrict__ out) {
    __shared__ float accs[4][16][128];
    __shared__ float rsums[4][16];

    int wave = threadIdx.x >> 6, lane = threadIdx.x & 63;
    int m = lane & 15, quad = lane >> 4;
    int i0 = blockIdx.x * 16;          // grid = 1250, 20000 = 1250*16 exactly
    int i = i0 + m;
    float wh1i = wh1[i];               // scaled by log2(e)
    // flash-style row offset: Mi >= every l in this row, minus 12 so the f16
    // P values land in [~0, 4096] (no overflow, no denormal mass loss)
    float emax = wh1i + maxwh2[0];
    float Mi = fmaxf(emax, 0.2f * emax) - 12.f;
    const int* frow = feat + (size_t)i * N_ATTRS;

    f32x4 acc[8];
#pragma unroll
    for (int nb = 0; nb < 8; ++nb)
#pragma unroll
        for (int t = 0; t < 4; ++t) acc[nb][t] = 0.f;
    float s = 0.f;

    int kk0 = wave * (KSTEPS / 4);
    int kk1 = kk0 + (KSTEPS / 4);
    for (int kk = kk0; kk < kk1; ++kk) {
        int jb = kk * 32 + quad * 8;   // 8 consecutive attrs for this lane
        int4 f0 = {0, 0, 0, 0}, f1 = {0, 0, 0, 0};
        if (jb < N_ATTRS) {            // 5000 % 8 == 0: chunk fully valid or fully pad
            f0 = *reinterpret_cast<const int4*>(frow + jb);
            f1 = *reinterpret_cast<const int4*>(frow + jb + 4);
        }
        float4 w2a = *reinterpret_cast<const float4*>(wh2 + jb);      // pad zeroed
        float4 w2b = *reinterpret_cast<const float4*>(wh2 + jb + 4);
        int   fi[8] = {f0.x, f0.y, f0.z, f0.w, f1.x, f1.y, f1.z, f1.w};
        float w2[8] = {w2a.x, w2a.y, w2a.z, w2a.w, w2b.x, w2b.y, w2b.z, w2b.w};
        f16x8 afrag;
#pragma unroll
        for (int t = 0; t < 8; ++t) {
            float e = wh1i + w2[t];            // log2e * raw score
            float l = fmaxf(e, 0.2f * e);      // leakyrelu (commutes with +scale)
            float p = fast_exp2(l - Mi);       // in (0, 4096]
            p = (fi[t] > 0) ? p : 0.f;         // mask (also kills K padding: fi==0)
            _Float16 ph = (_Float16)p;
            s += (float)ph;                    // sum the QUANTIZED p: weights sum to 1
            afrag[t] = ph;
        }
        const _Float16* vbase = Vp + (size_t)(kk * 8) * 64 * 8;
#pragma unroll
        for (int nb = 0; nb < 8; ++nb) {
            f16x8 bfrag;
            __builtin_memcpy(&bfrag, vbase + (nb * 64 + lane) * 8, 16);
            acc[nb] = __builtin_amdgcn_mfma_f32_16x16x32_f16(afrag, bfrag, acc[nb], 0, 0, 0);
        }
    }

    // row-sum: combine the 4 quads (lanes m, m+16, m+32, m+48 share row m)
    s += __shfl_xor(s, 16, 64);
    s += __shfl_xor(s, 32, 64);
    if (lane < 16) rsums[wave][lane] = s;

    // dump accumulators (C layout: row = quad*4+reg, col = nb*16 + m)
#pragma unroll
    for (int nb = 0; nb < 8; ++nb)
#pragma unroll
        for (int reg = 0; reg < 4; ++reg)
            accs[wave][quad * 4 + reg][nb * 16 + m] = acc[nb][reg];

    __syncthreads();

    // combine 4 K-partials, normalize, ELU, store fp32
    for (int o = threadIdx.x; o < 16 * 128; o += 256) {
        int lr = o >> 7, n = o & 127;
        float v = accs[0][lr][n] + accs[1][lr][n] + accs[2][lr][n] + accs[3][lr][n];
        float rs = rsums[0][lr] + rsums[1][lr] + rsums[2][lr] + rsums[3][lr];
        rs = (rs > 0.f) ? rs : 1.f;            // all-masked row guard (never hit here)
        float h = v / rs;
        float ov = (h > 0.f) ? h : (fast_exp2(h * LOG2E) - 1.f);  // ELU
        out[(size_t)(i0 + lr) * OUT_F + n] = ov;
    }
}

// ---------------------------------------------------------------------------
extern "C" void kernel_launch(void* const* d_in, const int* in_sizes, int n_in,
                              void* d_out, int out_size, void* d_ws, size_t ws_size,
                              hipStream_t stream) {
    const float* node_emb = (const float*)d_in[0];  // fp32 [20000,512]
    const float* attr_emb = (const float*)d_in[1];  // fp32 [5000,512]
    const int*   feat     = (const int*)d_in[2];    // int32 [20000,5000]
    const float* W        = (const float*)d_in[3];  // fp32 [512,128]
    const float* a        = (const float*)d_in[4];  // fp32 [256,1]
    float*       out      = (float*)d_out;          // fp32 [20000,128]

    char* ws = (char*)d_ws;
    float*    Wa1 = (float*)(ws + 0);          // 512 f32
    float*    Wa2 = (float*)(ws + 4096);       // 512 f32
    float*    wh1 = (float*)(ws + 8192);       // 20000 f32 (ends 88192)
    float*    wh2 = (float*)(ws + 90112);      // 5120 f32 incl. pad (ends 110592)
    float*    mx  = (float*)(ws + 110592);     // 1 f32
    _Float16* Wp  = (_Float16*)(ws + 131072);  // 65536 f16 (ends 262144)
    _Float16* Vp  = (_Float16*)(ws + 262144);  // 5120*128 f16 (ends 1572864)

    prep_kernel<<<64, 256, 0, stream>>>(W, a, Wa1, Wa2, Wp);
    wh_kernel<<<6250, 256, 0, stream>>>(node_emb, attr_emb, Wa1, Wa2, wh1, wh2);
    max_kernel<<<1, 256, 0, stream>>>(wh2, mx);
    attr_h_kernel<<<80, 256, 0, stream>>>(attr_emb, Wp, Vp);
    attn_kernel<<<1250, 256, 0, stream>>>(feat, wh1, wh2, mx, Vp, out);
}

// Round 3
// 689.538 us; speedup vs baseline: 1.0061x; 1.0061x over previous
//
#include <hip/hip_runtime.h>

// Problem constants
#define N_NODES 20000
#define N_ATTRS 5000
#define IN_F    512
#define OUT_F   128
#define KP      5120          // N_ATTRS padded to multiple of 32 (MFMA K)
#define KSTEPS  (KP / 32)     // 160
#define WH2_PAD 5376          // wh2 allocation: covers prefetch overrun, zeroed
#define LOG2E   1.4426950408889634f

typedef _Float16 f16x8 __attribute__((ext_vector_type(8)));
typedef float    f32x4 __attribute__((ext_vector_type(4)));

__device__ __forceinline__ float fast_exp2(float x) {
    return __builtin_amdgcn_exp2f(x);
}

// ---------------------------------------------------------------------------
// Kernel 1: Wa1 = W @ a[:128], Wa2 = W @ a[128:], both pre-scaled by log2(e);
// also repack W (fp32 [512x128] row-major) into f16 MFMA B-fragment order:
// idx = ((kb*8 + nb)*64 + lane)*8 + j  holds  W[kb*32 + (lane>>4)*8 + j][nb*16 + (lane&15)]
// ---------------------------------------------------------------------------
__global__ __launch_bounds__(256) void prep_kernel(
    const float* __restrict__ W, const float* __restrict__ a,
    float* __restrict__ Wa1, float* __restrict__ Wa2, _Float16* __restrict__ Wp) {
    int gt = blockIdx.x * blockDim.x + threadIdx.x;
    if (gt < IN_F) {
        int k = gt;
        float s1 = 0.f, s2 = 0.f;
        for (int f = 0; f < OUT_F; ++f) {
            float w = W[k * OUT_F + f];
            s1 += w * a[f];
            s2 += w * a[OUT_F + f];
        }
        Wa1[k] = s1 * LOG2E;   // fold log2(e): scores live in exp2 domain
        Wa2[k] = s2 * LOG2E;
    }
    for (int idx = gt; idx < IN_F * OUT_F; idx += gridDim.x * blockDim.x) {
        int j    = idx & 7;
        int lane = (idx >> 3) & 63;
        int nb   = (idx >> 9) & 7;
        int kb   = idx >> 12;
        int k = kb * 32 + (lane >> 4) * 8 + j;
        int n = nb * 16 + (lane & 15);
        Wp[idx] = (_Float16)W[k * OUT_F + n];
    }
}

// ---------------------------------------------------------------------------
// Kernel 2: wh1[i] = node_emb[i] . Wa1  (rows 0..19999)
//           wh2[j] = attr_emb[j] . Wa2  (rows 20000..24999)
// one wave per row; lane holds 8 consecutive fp32 (two 16B loads)
// ---------------------------------------------------------------------------
__global__ __launch_bounds__(256) void wh_kernel(
    const float* __restrict__ node_emb, const float* __restrict__ attr_emb,
    const float* __restrict__ Wa1, const float* __restrict__ Wa2,
    float* __restrict__ wh1, float* __restrict__ wh2) {
    int wave = threadIdx.x >> 6, lane = threadIdx.x & 63;
    int r = blockIdx.x * 4 + wave;   // grid = 6250 -> r in [0, 25000)
    const float* src;
    const float* vec;
    float* dst;
    if (r < N_NODES) {
        src = node_emb + (size_t)r * IN_F; vec = Wa1; dst = wh1 + r;
    } else {
        int r2 = r - N_NODES;
        src = attr_emb + (size_t)r2 * IN_F; vec = Wa2; dst = wh2 + r2;
    }
    float4 ra = *reinterpret_cast<const float4*>(src + lane * 8);
    float4 rb = *reinterpret_cast<const float4*>(src + lane * 8 + 4);
    const float* vp = vec + lane * 8;
    float s = ra.x * vp[0] + ra.y * vp[1] + ra.z * vp[2] + ra.w * vp[3]
            + rb.x * vp[4] + rb.y * vp[5] + rb.z * vp[6] + rb.w * vp[7];
#pragma unroll
    for (int off = 1; off < 64; off <<= 1) s += __shfl_xor(s, off, 64);
    if (lane == 0) *dst = s;
}

// ---------------------------------------------------------------------------
// Kernel 2b: maxwh2 = max_j wh2[j]; also zero the pad region of wh2
// (N_ATTRS..WH2_PAD covers the prefetch overrun). single block.
// ---------------------------------------------------------------------------
__global__ __launch_bounds__(256) void max_kernel(
    float* __restrict__ wh2, float* __restrict__ maxp) {
    __shared__ float red[4];
    int t = threadIdx.x;
    float m = -1e30f;
    for (int j = t; j < N_ATTRS; j += 256) m = fmaxf(m, wh2[j]);
    for (int j = N_ATTRS + t; j < WH2_PAD; j += 256) wh2[j] = 0.f;
#pragma unroll
    for (int off = 1; off < 64; off <<= 1) m = fmaxf(m, __shfl_xor(m, off, 64));
    int wave = t >> 6, lane = t & 63;
    if (lane == 0) red[wave] = m;
    __syncthreads();
    if (t == 0) *maxp = fmaxf(fmaxf(red[0], red[1]), fmaxf(red[2], red[3]));
}

// ---------------------------------------------------------------------------
// Kernel 3: V = attr_h = attr_emb @ W  [5120(pad) x 128] f16, stored directly
// in MFMA B-fragment-packed order for the main kernel:
// Vp[((kk*8 + nb)*64 + lane)*8 + jj] = V[kk*32 + (lane>>4)*8 + jj][nb*16 + (lane&15)]
// ---------------------------------------------------------------------------
__global__ __launch_bounds__(256) void attr_h_kernel(
    const float* __restrict__ attr_emb, const _Float16* __restrict__ Wp,
    _Float16* __restrict__ Vp) {
    int wave = threadIdx.x >> 6, lane = threadIdx.x & 63;
    int m = lane & 15, quad = lane >> 4;
    int j0 = (blockIdx.x * 4 + wave) * 16;  // grid = 80 -> j0 in [0, 5120)
    int j = j0 + m;
    bool valid = j < N_ATTRS;
    f32x4 acc[8];
#pragma unroll
    for (int nb = 0; nb < 8; ++nb)
#pragma unroll
        for (int t = 0; t < 4; ++t) acc[nb][t] = 0.f;
    const float* arow = attr_emb + (size_t)j * IN_F;
    for (int kk = 0; kk < IN_F / 32; ++kk) {
        f16x8 afrag;
        if (valid) {
            float4 ra = *reinterpret_cast<const float4*>(arow + kk * 32 + quad * 8);
            float4 rb = *reinterpret_cast<const float4*>(arow + kk * 32 + quad * 8 + 4);
            afrag[0] = (_Float16)ra.x; afrag[1] = (_Float16)ra.y;
            afrag[2] = (_Float16)ra.z; afrag[3] = (_Float16)ra.w;
            afrag[4] = (_Float16)rb.x; afrag[5] = (_Float16)rb.y;
            afrag[6] = (_Float16)rb.z; afrag[7] = (_Float16)rb.w;
        } else {
#pragma unroll
            for (int t = 0; t < 8; ++t) afrag[t] = (_Float16)0.f;
        }
        const _Float16* wbase = Wp + (size_t)(kk * 8) * 64 * 8;
#pragma unroll
        for (int nb = 0; nb < 8; ++nb) {
            f16x8 bfrag;
            __builtin_memcpy(&bfrag, wbase + (nb * 64 + lane) * 8, 16);
            acc[nb] = __builtin_amdgcn_mfma_f32_16x16x32_f16(afrag, bfrag, acc[nb], 0, 0, 0);
        }
    }
    // C/D layout: row = quad*4 + reg, col = lane&15 (within 16x16 tile)
#pragma unroll
    for (int nb = 0; nb < 8; ++nb) {
#pragma unroll
        for (int reg = 0; reg < 4; ++reg) {
            int jr = j0 + quad * 4 + reg;
            int n = nb * 16 + m;
            float v = (jr < N_ATTRS) ? acc[nb][reg] : 0.f;  // zero the K padding
            size_t idx = ((size_t)((jr >> 5) * 8 + nb) * 64 +
                          (((jr >> 3) & 3) * 16 + m)) * 8 + (jr & 7);
            Vp[idx] = (_Float16)v;
        }
    }
}

// ---------------------------------------------------------------------------
// Kernel 4 (main): per 16-node tile, stream feat_mat once, build P fragments
// (f16, flash-style rescaled so p <= 4096) in registers, MFMA into [16x128]
// fp32. 4 waves split K, 1-deep register prefetch of feat/wh2, serialized
// LDS accumulation (8.5 KB -> occupancy-friendly), normalize + ELU.
// ---------------------------------------------------------------------------
__global__ __launch_bounds__(256, 4) void attn_kernel(
    const int* __restrict__ feat, const float* __restrict__ wh1,
    const float* __restrict__ wh2, const float* __restrict__ maxwh2,
    const _Float16* __restrict__ Vp, float* __restrict__ out) {
    __shared__ float accs[16][132];   // +4 pad: quad-write conflicts -> 2-way (free)
    __shared__ float rsums[16];

    int wave = threadIdx.x >> 6, lane = threadIdx.x & 63;
    int m = lane & 15, quad = lane >> 4;
    int i0 = blockIdx.x * 16;          // grid = 1250, 20000 = 1250*16 exactly
    int i = i0 + m;
    float wh1i = wh1[i];               // scaled by log2(e)
    // flash-style row offset: Mi >= every l in this row, minus 12 so the f16
    // P values land in [~0, 4096] (no overflow, no denormal mass loss)
    float emax = wh1i + maxwh2[0];
    float Mi = fmaxf(emax, 0.2f * emax) - 12.f;
    const int* frow = feat + (size_t)i * N_ATTRS;

    f32x4 acc[8];
#pragma unroll
    for (int nb = 0; nb < 8; ++nb)
#pragma unroll
        for (int t = 0; t < 4; ++t) acc[nb][t] = 0.f;
    float s = 0.f;

    int kk0 = wave * (KSTEPS / 4);
    int kk1 = kk0 + (KSTEPS / 4);

    // ---- prologue: load kstep kk0 ----
    int jb = kk0 * 32 + quad * 8;
    int4 f0 = {0, 0, 0, 0}, f1 = {0, 0, 0, 0};
    if (jb < N_ATTRS) {                // 5000 % 8 == 0: chunk fully valid or pad
        f0 = *reinterpret_cast<const int4*>(frow + jb);
        f1 = *reinterpret_cast<const int4*>(frow + jb + 4);
    }
    float4 w2a = *reinterpret_cast<const float4*>(wh2 + jb);
    float4 w2b = *reinterpret_cast<const float4*>(wh2 + jb + 4);

    const _Float16* vbase = Vp + (size_t)(kk0 * 8) * 64 * 8;

    for (int kk = kk0; kk < kk1; ++kk) {
        // ---- prefetch kstep kk+1 (in flight across this iteration's work) ----
        int jbn = jb + 32;
        int4 nf0 = {0, 0, 0, 0}, nf1 = {0, 0, 0, 0};
        float4 nw2a = {0.f, 0.f, 0.f, 0.f}, nw2b = {0.f, 0.f, 0.f, 0.f};
        if (kk + 1 < kk1) {
            if (jbn < N_ATTRS) {
                nf0 = *reinterpret_cast<const int4*>(frow + jbn);
                nf1 = *reinterpret_cast<const int4*>(frow + jbn + 4);
            }
            nw2a = *reinterpret_cast<const float4*>(wh2 + jbn);   // pad zeroed to WH2_PAD
            nw2b = *reinterpret_cast<const float4*>(wh2 + jbn + 4);
        }

        // ---- P fragment from current kstep ----
        int   fi[8] = {f0.x, f0.y, f0.z, f0.w, f1.x, f1.y, f1.z, f1.w};
        float w2[8] = {w2a.x, w2a.y, w2a.z, w2a.w, w2b.x, w2b.y, w2b.z, w2b.w};
        f16x8 afrag;
#pragma unroll
        for (int t = 0; t < 8; ++t) {
            float e = wh1i + w2[t];            // log2e * raw score
            float l = fmaxf(e, 0.2f * e);      // leakyrelu (commutes with +scale)
            float p = fast_exp2(l - Mi);       // in (0, 4096]
            p = (fi[t] > 0) ? p : 0.f;         // mask (also kills K padding: fi==0)
            _Float16 ph = (_Float16)p;
            s += (float)ph;                    // sum the QUANTIZED p: weights sum to 1
            afrag[t] = ph;
        }

        // ---- 8 MFMA against L2-resident Vp fragments ----
#pragma unroll
        for (int nb = 0; nb < 8; ++nb) {
            f16x8 bfrag;
            __builtin_memcpy(&bfrag, vbase + (nb * 64 + lane) * 8, 16);
            acc[nb] = __builtin_amdgcn_mfma_f32_16x16x32_f16(afrag, bfrag, acc[nb], 0, 0, 0);
        }

        // ---- rotate prefetch ----
        f0 = nf0; f1 = nf1; w2a = nw2a; w2b = nw2b; jb = jbn;
        vbase += 8 * 64 * 8;
    }

    // row-sum: combine the 4 quads (lanes m, m+16, m+32, m+48 share row m)
    s += __shfl_xor(s, 16, 64);
    s += __shfl_xor(s, 32, 64);

    // serialized cross-wave accumulation into one 16x128 buffer (4 barriers)
#pragma unroll
    for (int w = 0; w < 4; ++w) {
        if (wave == w) {
            if (w == 0) {
#pragma unroll
                for (int nb = 0; nb < 8; ++nb)
#pragma unroll
                    for (int reg = 0; reg < 4; ++reg)
                        accs[quad * 4 + reg][nb * 16 + m] = acc[nb][reg];
                if (lane < 16) rsums[lane] = s;
            } else {
#pragma unroll
                for (int nb = 0; nb < 8; ++nb)
#pragma unroll
                    for (int reg = 0; reg < 4; ++reg)
                        accs[quad * 4 + reg][nb * 16 + m] += acc[nb][reg];
                if (lane < 16) rsums[lane] += s;
            }
        }
        __syncthreads();
    }

    // normalize, ELU, store fp32
    for (int o = threadIdx.x; o < 16 * 128; o += 256) {
        int lr = o >> 7, n = o & 127;
        float v = accs[lr][n];
        float rs = rsums[lr];
        rs = (rs > 0.f) ? rs : 1.f;            // all-masked row guard (never hit here)
        float h = v / rs;
        float ov = (h > 0.f) ? h : (fast_exp2(h * LOG2E) - 1.f);  // ELU
        out[(size_t)(i0 + lr) * OUT_F + n] = ov;
    }
}

// ---------------------------------------------------------------------------
extern "C" void kernel_launch(void* const* d_in, const int* in_sizes, int n_in,
                              void* d_out, int out_size, void* d_ws, size_t ws_size,
                              hipStream_t stream) {
    const float* node_emb = (const float*)d_in[0];  // fp32 [20000,512]
    const float* attr_emb = (const float*)d_in[1];  // fp32 [5000,512]
    const int*   feat     = (const int*)d_in[2];    // int32 [20000,5000]
    const float* W        = (const float*)d_in[3];  // fp32 [512,128]
    const float* a        = (const float*)d_in[4];  // fp32 [256,1]
    float*       out      = (float*)d_out;          // fp32 [20000,128]

    char* ws = (char*)d_ws;
    float*    Wa1 = (float*)(ws + 0);          // 512 f32
    float*    Wa2 = (float*)(ws + 4096);       // 512 f32
    float*    wh1 = (float*)(ws + 8192);       // 20000 f32 (ends 88192)
    float*    wh2 = (float*)(ws + 90112);      // 5376 f32 incl. zeroed pad (ends 111616)
    float*    mx  = (float*)(ws + 111616);     // 1 f32
    _Float16* Wp  = (_Float16*)(ws + 131072);  // 65536 f16 (ends 262144)
    _Float16* Vp  = (_Float16*)(ws + 262144);  // 5120*128 f16 (ends 1572864)

    prep_kernel<<<64, 256, 0, stream>>>(W, a, Wa1, Wa2, Wp);
    wh_kernel<<<6250, 256, 0, stream>>>(node_emb, attr_emb, Wa1, Wa2, wh1, wh2);
    max_kernel<<<1, 256, 0, stream>>>(wh2, mx);
    attr_h_kernel<<<80, 256, 0, stream>>>(attr_emb, Wp, Vp);
    attn_kernel<<<1250, 256, 0, stream>>>(feat, wh1, wh2, mx, Vp, out);
}